// Round 15
// baseline (117.771 us; speedup 1.0000x reference)
//
#include <hip/hip_runtime.h>
#include <math.h>

#define BB 4
#define CC 64
#define HH_ 128
#define WW 128
#define HPW (HH_*WW)     // 16384
#define KH 64
#define KW 64
#define KSZ 7
#define AA 16
#define EPSV 1e-5f
#define KTOT 448         // 7*64

typedef __attribute__((ext_vector_type(8))) short bf16x8;
typedef __attribute__((ext_vector_type(4))) float f32x4;
typedef unsigned short ushort_t;

__device__ __forceinline__ float sigm(float x){ return 1.0f/(1.0f+expf(-x)); }
__device__ __forceinline__ unsigned short f2bf(float f){
  unsigned u = __float_as_uint(f);
  return (unsigned short)((u + 0x7fffu + ((u>>16)&1u)) >> 16);
}

// ---------------- K1: prep + DWT-HH + mean partials (512 x 512) ----------------
__global__ __launch_bounds__(512) void k_dwt0(const float* __restrict__ x,
  const float* __restrict__ dsw, const float* __restrict__ offw,
  float* __restrict__ HHb, float* __restrict__ partial,
  ushort_t* __restrict__ dsWbf, ushort_t* __restrict__ offAbf)
{
  int t = threadIdx.x; int wg = blockIdx.x;
  int idx = wg*512 + t;
  if(idx < CC*KTOT){
    int co = idx/KTOT; int K = idx%KTOT; int k = K>>6; int ci = K&63;
    dsWbf[idx] = f2bf(dsw[(size_t)(co*CC+ci)*KSZ + k]);
  } else {
    int j2 = idx - CC*KTOT;
    if(j2 < 18*16*32){
      int kl = j2&31; int co = (j2>>5)&15; int s = j2>>9;
      int tap = s>>1; int ci = (s&1)*32 + kl;
      float v = 0.f;
      if(co<KSZ) v = offw[((size_t)co*CC + ci)*9 + tap];
      offAbf[j2] = f2bf(v);
    }
  }
  int lane = t&63, wid = t>>6;
  int e0 = wg*2048 + t*4;
  int bc = e0>>12; int h2 = (e0>>6)&63; int w0 = e0&63;
  const float* xp = x + (size_t)bc*HPW;
  float4 a0 = *(const float4*)(xp + (2*h2)*WW + 2*w0);
  float4 a1 = *(const float4*)(xp + (2*h2)*WW + 2*w0 + 4);
  float4 b0 = *(const float4*)(xp + (2*h2+1)*WW + 2*w0);
  float4 b1 = *(const float4*)(xp + (2*h2+1)*WW + 2*w0 + 4);
  float4 hh;
  hh.x = 0.5f*(a0.x - b0.x - a0.y + b0.y);
  hh.y = 0.5f*(a0.z - b0.z - a0.w + b0.w);
  hh.z = 0.5f*(a1.x - b1.x - a1.y + b1.y);
  hh.w = 0.5f*(a1.z - b1.z - a1.w + b1.w);
  *(float4*)(HHb + e0) = hh;
  float s = a0.x+a0.y+a0.z+a0.w + a1.x+a1.y+a1.z+a1.w
          + b0.x+b0.y+b0.z+b0.w + b1.x+b1.y+b1.z+b1.w;
  for(int o=32;o>0;o>>=1) s += __shfl_down(s,o);
  __shared__ float ls[8];
  if(lane==0) ls[wid] = s;
  __syncthreads();
  if(t==0){
    float tot=0.f;
    #pragma unroll
    for(int k2=0;k2<8;k2++) tot += ls[k2];
    partial[wg] = tot;
  }
}

// ---------------- K2: attention + weff, grid (b,o), 64 thr ----------------
__global__ __launch_bounds__(64) void k_weff2(const float* __restrict__ partial,
  const float* __restrict__ w, const float* __restrict__ ratio_p,
  const float* __restrict__ o1fc, const float* __restrict__ o1g,const float* __restrict__ o1b,
  const float* __restrict__ o1m,const float* __restrict__ o1v,
  const float* __restrict__ o1cw,const float* __restrict__ o1cb,
  const float* __restrict__ o1fw,const float* __restrict__ o1fb,
  const float* __restrict__ o2fc, const float* __restrict__ o2g,const float* __restrict__ o2b,
  const float* __restrict__ o2m,const float* __restrict__ o2v,
  const float* __restrict__ o2cw,const float* __restrict__ o2cb,
  const float* __restrict__ o2fw,const float* __restrict__ o2fb,
  const float* __restrict__ spw,const float* __restrict__ spb,
  float* __restrict__ weff)
{
  int bo = blockIdx.x; int b = bo>>6, o = bo&63; int ci = threadIdx.x;
  int bc = b*CC+ci;
  float g_own = (partial[2*bc] + partial[2*bc+1]) * (1.0f/HPW);
  float d1=o1cb[ci], d2=o1fb[ci], d3=o2cb[ci], d4=o2fb[ci];
  float sspacc[9];
  #pragma unroll
  for(int e=0;e<9;e++) sspacc[e]=spb[e];
  for(int j=0;j<AA;j++){
    float p1 = g_own * o1fc[j*CC+ci];
    float p2 = g_own * o2fc[j*CC+ci];
    #pragma unroll
    for(int off=32;off>0;off>>=1){ p1+=__shfl_xor(p1,off); p2+=__shfl_xor(p2,off); }
    p1 = (p1-o1m[j])*rsqrtf(o1v[j]+EPSV)*o1g[j]+o1b[j]; p1=fmaxf(p1,0.f);
    p2 = (p2-o2m[j])*rsqrtf(o2v[j]+EPSV)*o2g[j]+o2b[j]; p2=fmaxf(p2,0.f);
    d1 += p1*o1cw[ci*AA+j]; d2 += p1*o1fw[ci*AA+j];
    d3 += p2*o2cw[ci*AA+j]; d4 += p2*o2fw[ci*AA+j];
    #pragma unroll
    for(int e=0;e<9;e++) sspacc[e] += p2*spw[e*AA+j];
  }
  float sc1v=sigm(d1), sc2v=sigm(d3);
  float sf1o=__shfl(sigm(d2),o), sf2o=__shfl(sigm(d4),o);
  const float* wp = w + (size_t)(o*CC+ci)*9;
  float w9[9]; float m=0.f;
  #pragma unroll
  for(int e=0;e<9;e++){ w9[e]=wp[e]; m+=w9[e]; }
  m *= (1.0f/9.0f);
  float S1 = m * sc1v;
  float M[9];
  #pragma unroll
  for(int e=0;e<9;e++) M[e] = (w9[e]-m)*sc2v;
  #pragma unroll
  for(int off=32; off>0; off>>=1){
    S1 += __shfl_xor(S1, off);
    #pragma unroll
    for(int e=0;e<9;e++) M[e] += __shfl_xor(M[e], off);
  }
  if(ci==0){
    const float Dm[3][3] = {{2.f,2.f,2.f},{1.7320508075688772f,0.f,-1.7320508075688772f},{1.f,-2.f,1.f}};
    const float Di[3][3] = {{0.16666666666666666f,0.28867513459481287f,0.16666666666666666f},
                            {0.16666666666666666f,0.f,-0.3333333333333333f},
                            {0.16666666666666666f,-0.28867513459481287f,0.16666666666666666f}};
    float U[3][3], T[3][3], V[3][3], R[3][3];
    for(int k=0;k<3;k++)for(int n=0;n<3;n++) U[k][n]=Dm[k][0]*M[0*3+n]+Dm[k][1]*M[1*3+n]+Dm[k][2]*M[2*3+n];
    for(int k=0;k<3;k++)for(int l=0;l<3;l++) T[k][l]=(U[k][0]*Dm[l][0]+U[k][1]*Dm[l][1]+U[k][2]*Dm[l][2])*2.0f*sigm(sspacc[k*3+l]);
    for(int k=0;k<3;k++)for(int n=0;n<3;n++) V[k][n]=Di[k][0]*T[0][n]+Di[k][1]*T[1][n]+Di[k][2]*T[2][n];
    for(int k=0;k<3;k++)for(int l=0;l<3;l++) R[k][l]=V[k][0]*Di[l][0]+V[k][1]*Di[l][1]+V[k][2]*Di[l][2];
    float rr = ratio_p[0];
    float base = rr*4.0f*sf1o*S1;
    float w2f = (1.0f-rr)*4.0f*sf2o;
    #pragma unroll
    for(int e=0;e<9;e++) weff[(size_t)bo*9+e] = base + w2f*R[e/3][e%3];
  }
}

// ---------------- K3: iwt + transpose, 2 output rows per block ----------------
__global__ __launch_bounds__(256) void k_iwtT(const float* __restrict__ HHb,
  const float* __restrict__ x, const float* __restrict__ weff,
  float* __restrict__ outT, ushort_t* __restrict__ outTbf)
{
  __shared__ __align__(16) char smem[33024 + 16640];
  float* hs  = (float*)smem;             // [32][3][66]
  float* xt  = (float*)smem;             // [64][129] (reused after conv)
  float* d_s = (float*)(smem + 33024);   // [64][65]
  int wg = blockIdx.x; int b = wg>>6, h2 = wg&63;
  int t = threadIdx.x;
  #pragma unroll
  for(int half=0; half<2; ++half){
    for(int e=t; e<32*3*66; e+=256){
      int c_l = e/198; int rem = e - c_l*198; int r3 = rem/66; int wz = rem - r3*66;
      int r = h2 - 1 + r3; int w2 = wz - 1;
      int c = half*32 + c_l;
      float v = 0.f;
      if(r>=0 && r<KH && w2>=0 && w2<KW)
        v = HHb[((size_t)(b*CC+c))*(KH*KW) + r*KW + w2];
      hs[(c_l*3 + r3)*66 + wz] = v;
    }
    __syncthreads();
    {
      int c_l = t>>3, q = t&7;
      int c = half*32 + c_l;
      float wk[9];
      #pragma unroll
      for(int e=0;e<9;e++) wk[e] = weff[(size_t)(b*CC+c)*9+e];
      const float* hb = hs + c_l*198;
      #pragma unroll
      for(int j=0;j<8;j++){
        int w2 = q*8+j;
        float conv = 0.f;
        #pragma unroll
        for(int dh=0;dh<3;dh++){
          const float* hr = hb + dh*66 + w2;
          conv += wk[dh*3+0]*hr[0] + wk[dh*3+1]*hr[1] + wk[dh*3+2]*hr[2];
        }
        d_s[c*65+w2] = 0.5f*(conv - hb[1*66 + w2 + 1]);
      }
    }
    __syncthreads();
  }
  #pragma unroll
  for(int r=0;r<2;r++){
    int h = 2*h2 + r;
    for(int e=t; e<CC*WW; e+=256){
      int cc=e>>7, w=e&127;
      xt[cc*129+w] = x[((size_t)(b*CC+cc)*HH_+h)*WW + w];
    }
    __syncthreads();
    float* dst = outT + ((size_t)(b*HH_+h))*WW*CC;
    ushort_t* dstb = outTbf + ((size_t)(b*HH_+h))*130*CC;
    for(int e=t; e<CC*WW; e+=256){
      int w=e>>6, cc=e&63;
      float dv = d_s[cc*65+(w>>1)];
      float val = 2.f*xt[cc*129+w] + (((h + w)&1) ? -dv : dv);
      dst[e] = val;
      dstb[(w+1)*CC + cc] = f2bf(val);
    }
    if(t<128){ int cc=t&63; int side=t>>6; dstb[(size_t)side*129*CC + cc] = 0; }
    __syncthreads();
  }
}

// ---------------- K4: fused offset-conv + dy + deform-sample GEMM + GN partials ----------------
// Phase D: per-wave private LDS slice, NO block barriers. Wave wid owns pos tile
// [wid*16,+16) and computes all 64 co for it.
__global__ __launch_bounds__(512) void k_dsfused(const float* __restrict__ outT,
  const ushort_t* __restrict__ outTbf, const ushort_t* __restrict__ dsWbf,
  const ushort_t* __restrict__ offAbf, const float* __restrict__ offb,
  const float* __restrict__ obg, const float* __restrict__ obb,
  const float* __restrict__ obm, const float* __restrict__ obv,
  const float* __restrict__ dsb, float* __restrict__ yout, float* __restrict__ pstats)
{
  __shared__ ushort_t S2a[2*8192];        // per wave: 2 buffers x 1024 shorts (2KB)
  __shared__ int sb0[KSZ*128], sb1[KSZ*128];
  __shared__ float swr[KSZ*128];
  __shared__ float off_s[KSZ*128];
  __shared__ float dy_s[KSZ*128];
  int t = threadIdx.x;
  int wg = blockIdx.x; int sw = (wg&7)*64 + (wg>>3);   // XCD swizzle
  int b = sw>>7, h = sw&127;
  int lane = t&63, wid = t>>6;
  int arow = lane&15, kgrp = lane>>4;
  // ---- Phase A: offset conv (8 waves, wave = one 16-wide w tile) ----
  {
    f32x4 acc = (f32x4){0.f,0.f,0.f,0.f};
    #pragma unroll
    for(int s=0;s<18;s++){
      int tap = s>>1, chalf = s&1;
      int r = tap/3, dwp = tap%3;
      int hr = h - 1 + r;
      if(hr<0 || hr>=HH_) continue;
      bf16x8 aF = *(const bf16x8*)(offAbf + (s*16+arow)*32 + kgrp*8);
      const ushort_t* base = outTbf + ((size_t)(b*HH_+hr))*130*CC + chalf*32 + kgrp*8;
      int wp = (wid<<4) + arow + dwp;
      bf16x8 bF = *(const bf16x8*)(base + (size_t)wp*CC);
      acc = __builtin_amdgcn_mfma_f32_16x16x32_bf16(aF, bF, acc, 0,0,0);
    }
    #pragma unroll
    for(int r=0;r<4;r++){
      int co = kgrp*4+r;
      if(co<KSZ) off_s[co*128 + (wid<<4) + arow] = acc[r];
    }
  }
  __syncthreads();
  // ---- Phase B: BN + tanh + cumsum ----
  if(t<128){
    int w = t;
    float y[KSZ];
    #pragma unroll
    for(int k=0;k<KSZ;k++){
      float sc = obg[k]*rsqrtf(obv[k]+EPSV);
      float sh = obb[k]-obm[k]*sc;
      y[k] = tanhf((off_s[k*128+w]+offb[k])*sc+sh);
    }
    dy_s[      w]=y[0]+y[1]+y[2]; dy_s[128+w]=y[1]+y[2]; dy_s[256+w]=y[2];
    dy_s[384+w]=0.f; dy_s[512+w]=y[4]; dy_s[640+w]=y[4]+y[5]; dy_s[768+w]=y[4]+y[5]+y[6];
  }
  __syncthreads();
  // ---- Phase C: sample meta ----
  for(int e=t; e<KSZ*128; e+=512){
    int k = e>>7, w = e&127;
    float dv = dy_s[e];
    float r = fminf(fmaxf((float)h + dv, 0.f), 127.f);
    float rf = floorf(r); int r0=(int)rf; float wr=r-rf; int r1=min(r0+1,127);
    int c = min(max(w+k-3,0),127);
    sb0[k*128+w] = ((b*HH_+r0)*WW+c)*CC;
    sb1[k*128+w] = ((b*HH_+r1)*WW+c)*CC;
    swr[k*128+w] = wr;
  }
  __syncthreads();
  // ---- Phase D: per-wave barrier-free K-chunked GEMM ----
  ushort_t* Sw = S2a + wid*2048;          // this wave's 2x1024-short region
  int rsub = lane>>4;                     // 0..3
  int ciq  = (lane&15)<<2;                // float quad index 0,4,..,60
  // fill chunk k into buffer buf (per-wave private)
  auto fill = [&](int k, ushort_t* buf){
    #pragma unroll
    for(int i=0;i<4;i++){
      int pl = i*4 + rsub;                // local pos 0..15
      int e  = k*128 + (wid<<4) + pl;
      float4 v0 = *(const float4*)(outT + sb0[e] + ciq);
      float4 v1 = *(const float4*)(outT + sb1[e] + ciq);
      float wr = swr[e];
      unsigned lo = (unsigned)f2bf(v0.x + wr*(v1.x-v0.x)) | ((unsigned)f2bf(v0.y + wr*(v1.y-v0.y))<<16);
      unsigned hi = (unsigned)f2bf(v0.z + wr*(v1.z-v0.z)) | ((unsigned)f2bf(v0.w + wr*(v1.w-v0.w))<<16);
      int off = (pl*128 + ciq*2) ^ ((pl&7)<<4);
      *(uint2*)((char*)buf + off) = make_uint2(lo,hi);
    }
  };
  f32x4 acc[4];
  #pragma unroll
  for(int cg=0;cg<4;cg++) acc[cg] = (f32x4){0.f,0.f,0.f,0.f};
  fill(0, Sw);
  int bufs = 0;
  int roff0 = (arow*128 + kgrp*16) ^ ((arow&7)<<4);
  int roff1 = (arow*128 + 64 + kgrp*16) ^ ((arow&7)<<4);
  for(int k=0;k<KSZ;k++){
    // 1. read this chunk's B-frags into registers (waits only on own fill)
    const char* cb = (const char*)(Sw + bufs*1024);
    bf16x8 b0 = *(const bf16x8*)(cb + roff0);
    bf16x8 b1 = *(const bf16x8*)(cb + roff1);
    // 2. issue next chunk's fill (independent of the MFMAs below)
    if(k+1<KSZ) fill(k+1, Sw + (bufs^1)*1024);
    // 3. MFMAs from registers
    #pragma unroll
    for(int cg=0;cg<4;cg++){
      const ushort_t* Wp = dsWbf + (size_t)((cg<<4)+arow)*KTOT + (k<<6) + kgrp*8;
      bf16x8 a0 = *(const bf16x8*)Wp;
      bf16x8 a1 = *(const bf16x8*)(Wp+32);
      acc[cg] = __builtin_amdgcn_mfma_f32_16x16x32_bf16(a0, b0, acc[cg], 0,0,0);
      acc[cg] = __builtin_amdgcn_mfma_f32_16x16x32_bf16(a1, b1, acc[cg], 0,0,0);
    }
    bufs ^= 1;
  }
  // ---- epilogue: y + GN partials (wave-private w-tile) ----
  float vs[16], vq[16];
  #pragma unroll
  for(int cg=0;cg<4;cg++){
    #pragma unroll
    for(int r=0;r<4;r++){
      int co = (cg<<4) + kgrp*4 + r;
      float y = acc[cg][r] + dsb[co];
      int wcol = (wid<<4) + arow;
      yout[((size_t)(b*CC+co)*HH_ + h)*WW + wcol] = y;
      vs[cg*4+r] = y; vq[cg*4+r] = y*y;
    }
  }
  #pragma unroll
  for(int m=1;m<16;m<<=1){
    #pragma unroll
    for(int i=0;i<16;i++){ vs[i]+=__shfl_xor(vs[i],m); vq[i]+=__shfl_xor(vq[i],m); }
  }
  if(arow==0){
    #pragma unroll
    for(int cg=0;cg<4;cg++){
      #pragma unroll
      for(int r=0;r<4;r++){
        int co = (cg<<4)+kgrp*4+r;
        int pi = (b*CC+co)*1024 + h*8 + wid;
        pstats[pi] = vs[cg*4+r];
        pstats[262144+pi] = vq[cg*4+r];
      }
    }
  }
}

// ---------------- K5: reduce GN partials -> group stats ----------------
__global__ __launch_bounds__(256) void k_gnfin2(const float* __restrict__ pstats,
                                                float* __restrict__ gstat){
  int bg = blockIdx.x; int b = bg>>4, g = bg&15; int t = threadIdx.x;
  float s=0.f, q=0.f;
  #pragma unroll
  for(int c4=0;c4<4;c4++){
    int base = (b*CC + g*4+c4)*1024;
    for(int i=t;i<1024;i+=256){
      s += pstats[base + i];
      q += pstats[262144 + base + i];
    }
  }
  for(int o=32;o>0;o>>=1){ s+=__shfl_down(s,o); q+=__shfl_down(q,o); }
  __shared__ float ls[4], lq[4];
  if((t&63)==0){ ls[t>>6]=s; lq[t>>6]=q; }
  __syncthreads();
  if(t==0){
    float S=ls[0]+ls[1]+ls[2]+ls[3], Q=lq[0]+lq[1]+lq[2]+lq[3];
    float inv = 1.0f/(4.0f*HPW);
    float mu = S*inv; float var = Q*inv - mu*mu;
    gstat[bg*2]=mu; gstat[bg*2+1]=rsqrtf(var+EPSV);
  }
}

// ---------------- K6: apply GN + affine + relu in place ----------------
__global__ void k_gnapply(float* __restrict__ y, const float* __restrict__ gstat,
  const float* __restrict__ gg, const float* __restrict__ gb){
  int idx = blockIdx.x*256 + threadIdx.x;
  float4* p = (float4*)y;
  int bc = idx >> 12;
  int b = bc>>6, c = bc&63;
  int gi = b*16 + (c>>2);
  float mu = gstat[gi*2], rstd = gstat[gi*2+1];
  float sc = rstd*gg[c], sh = gb[c]-mu*sc;
  float4 v = p[idx];
  v.x = fmaxf(v.x*sc+sh, 0.f);
  v.y = fmaxf(v.y*sc+sh, 0.f);
  v.z = fmaxf(v.z*sc+sh, 0.f);
  v.w = fmaxf(v.w*sc+sh, 0.f);
  p[idx] = v;
}

extern "C" void kernel_launch(void* const* d_in, const int* in_sizes, int n_in,
                              void* d_out, int out_size, void* d_ws, size_t ws_size,
                              hipStream_t stream) {
  const float* x      = (const float*)d_in[0];
  const float* weight = (const float*)d_in[1];
  const float* ratio  = (const float*)d_in[2];
  const float* o1fc   = (const float*)d_in[3];
  const float* o1g    = (const float*)d_in[4];
  const float* o1b    = (const float*)d_in[5];
  const float* o1m    = (const float*)d_in[6];
  const float* o1v    = (const float*)d_in[7];
  const float* o1cw   = (const float*)d_in[8];
  const float* o1cb   = (const float*)d_in[9];
  const float* o1fw   = (const float*)d_in[10];
  const float* o1fb   = (const float*)d_in[11];
  const float* o2fc   = (const float*)d_in[12];
  const float* o2g    = (const float*)d_in[13];
  const float* o2b    = (const float*)d_in[14];
  const float* o2m    = (const float*)d_in[15];
  const float* o2v    = (const float*)d_in[16];
  const float* o2cw   = (const float*)d_in[17];
  const float* o2cb   = (const float*)d_in[18];
  const float* o2fw   = (const float*)d_in[19];
  const float* o2fb   = (const float*)d_in[20];
  const float* spw    = (const float*)d_in[21];
  const float* spb    = (const float*)d_in[22];
  const float* offw   = (const float*)d_in[23];
  const float* offb   = (const float*)d_in[24];
  const float* obg    = (const float*)d_in[25];
  const float* obb    = (const float*)d_in[26];
  const float* obm    = (const float*)d_in[27];
  const float* obv    = (const float*)d_in[28];
  const float* dsw    = (const float*)d_in[29];
  const float* dsb    = (const float*)d_in[30];
  const float* gng    = (const float*)d_in[31];
  const float* gnb    = (const float*)d_in[32];

  float* ws    = (float*)d_ws;
  float* HHb   = ws;                            // 1048576
  float* partial = ws + 1048576;                // 512
  float* weff  = ws + 1049088;                  // 2304
  float* gstat = ws + 1051392;                  // 128
  ushort_t* dsWbf  = (ushort_t*)(ws + 1051520); // 28672 shorts
  ushort_t* offAbf = (ushort_t*)(ws + 1065856); // 9216 shorts
  float* pstats= ws + 1070464;                  // 524288
  float* outT  = ws + 1594752;                  // 4194304
  ushort_t* outTbf = (ushort_t*)(ws + 5789056); // 4*128*130*64 shorts
  float* outb  = (float*)d_out;

  k_dwt0<<<512,512,0,stream>>>(x, dsw, offw, HHb, partial, dsWbf, offAbf);
  k_weff2<<<256,64,0,stream>>>(partial, weight, ratio,
    o1fc,o1g,o1b,o1m,o1v,o1cw,o1cb,o1fw,o1fb,
    o2fc,o2g,o2b,o2m,o2v,o2cw,o2cb,o2fw,o2fb,
    spw,spb, weff);
  k_iwtT<<<256,256,0,stream>>>(HHb, x, weff, outT, outTbf);
  k_dsfused<<<512,512,0,stream>>>(outT, outTbf, dsWbf, offAbf,
    offb, obg, obb, obm, obv, dsb, outb, pstats);
  k_gnfin2<<<64,256,0,stream>>>(pstats, gstat);
  k_gnapply<<<4096,256,0,stream>>>(outb, gstat, gng, gnb);
}

// Round 16
// 85.919 us; speedup vs baseline: 1.3707x; 1.3707x over previous
//
#include <hip/hip_runtime.h>
#include <math.h>

#define BB 4
#define CC 64
#define HH_ 128
#define WW 128
#define HPW (HH_*WW)     // 16384
#define KH 64
#define KW 64
#define KSZ 7
#define AA 16
#define EPSV 1e-5f
#define KTOT 448         // 7*64

typedef __attribute__((ext_vector_type(8))) short bf16x8;
typedef __attribute__((ext_vector_type(4))) float f32x4;
typedef unsigned short ushort_t;

__device__ __forceinline__ float sigm(float x){ return 1.0f/(1.0f+expf(-x)); }
__device__ __forceinline__ unsigned short f2bf(float f){
  unsigned u = __float_as_uint(f);
  return (unsigned short)((u + 0x7fffu + ((u>>16)&1u)) >> 16);
}

// ---------------- K1: prep + DWT-HH + mean partials (512 x 512) ----------------
__global__ __launch_bounds__(512) void k_dwt0(const float* __restrict__ x,
  const float* __restrict__ dsw, const float* __restrict__ offw,
  float* __restrict__ HHb, float* __restrict__ partial,
  ushort_t* __restrict__ dsWbf, ushort_t* __restrict__ offAbf)
{
  int t = threadIdx.x; int wg = blockIdx.x;
  int idx = wg*512 + t;
  if(idx < CC*KTOT){
    int co = idx/KTOT; int K = idx%KTOT; int k = K>>6; int ci = K&63;
    dsWbf[idx] = f2bf(dsw[(size_t)(co*CC+ci)*KSZ + k]);
  } else {
    int j2 = idx - CC*KTOT;
    if(j2 < 18*16*32){
      int kl = j2&31; int co = (j2>>5)&15; int s = j2>>9;
      int tap = s>>1; int ci = (s&1)*32 + kl;
      float v = 0.f;
      if(co<KSZ) v = offw[((size_t)co*CC + ci)*9 + tap];
      offAbf[j2] = f2bf(v);
    }
  }
  int lane = t&63, wid = t>>6;
  int e0 = wg*2048 + t*4;
  int bc = e0>>12; int h2 = (e0>>6)&63; int w0 = e0&63;
  const float* xp = x + (size_t)bc*HPW;
  float4 a0 = *(const float4*)(xp + (2*h2)*WW + 2*w0);
  float4 a1 = *(const float4*)(xp + (2*h2)*WW + 2*w0 + 4);
  float4 b0 = *(const float4*)(xp + (2*h2+1)*WW + 2*w0);
  float4 b1 = *(const float4*)(xp + (2*h2+1)*WW + 2*w0 + 4);
  float4 hh;
  hh.x = 0.5f*(a0.x - b0.x - a0.y + b0.y);
  hh.y = 0.5f*(a0.z - b0.z - a0.w + b0.w);
  hh.z = 0.5f*(a1.x - b1.x - a1.y + b1.y);
  hh.w = 0.5f*(a1.z - b1.z - a1.w + b1.w);
  *(float4*)(HHb + e0) = hh;
  float s = a0.x+a0.y+a0.z+a0.w + a1.x+a1.y+a1.z+a1.w
          + b0.x+b0.y+b0.z+b0.w + b1.x+b1.y+b1.z+b1.w;
  for(int o=32;o>0;o>>=1) s += __shfl_down(s,o);
  __shared__ float ls[8];
  if(lane==0) ls[wid] = s;
  __syncthreads();
  if(t==0){
    float tot=0.f;
    #pragma unroll
    for(int k2=0;k2<8;k2++) tot += ls[k2];
    partial[wg] = tot;
  }
}

// ---------------- K2: attention + weff, grid (b,o), 64 thr ----------------
__global__ __launch_bounds__(64) void k_weff2(const float* __restrict__ partial,
  const float* __restrict__ w, const float* __restrict__ ratio_p,
  const float* __restrict__ o1fc, const float* __restrict__ o1g,const float* __restrict__ o1b,
  const float* __restrict__ o1m,const float* __restrict__ o1v,
  const float* __restrict__ o1cw,const float* __restrict__ o1cb,
  const float* __restrict__ o1fw,const float* __restrict__ o1fb,
  const float* __restrict__ o2fc, const float* __restrict__ o2g,const float* __restrict__ o2b,
  const float* __restrict__ o2m,const float* __restrict__ o2v,
  const float* __restrict__ o2cw,const float* __restrict__ o2cb,
  const float* __restrict__ o2fw,const float* __restrict__ o2fb,
  const float* __restrict__ spw,const float* __restrict__ spb,
  float* __restrict__ weff)
{
  int bo = blockIdx.x; int b = bo>>6, o = bo&63; int ci = threadIdx.x;
  int bc = b*CC+ci;
  float g_own = (partial[2*bc] + partial[2*bc+1]) * (1.0f/HPW);
  float d1=o1cb[ci], d2=o1fb[ci], d3=o2cb[ci], d4=o2fb[ci];
  float sspacc[9];
  #pragma unroll
  for(int e=0;e<9;e++) sspacc[e]=spb[e];
  for(int j=0;j<AA;j++){
    float p1 = g_own * o1fc[j*CC+ci];
    float p2 = g_own * o2fc[j*CC+ci];
    #pragma unroll
    for(int off=32;off>0;off>>=1){ p1+=__shfl_xor(p1,off); p2+=__shfl_xor(p2,off); }
    p1 = (p1-o1m[j])*rsqrtf(o1v[j]+EPSV)*o1g[j]+o1b[j]; p1=fmaxf(p1,0.f);
    p2 = (p2-o2m[j])*rsqrtf(o2v[j]+EPSV)*o2g[j]+o2b[j]; p2=fmaxf(p2,0.f);
    d1 += p1*o1cw[ci*AA+j]; d2 += p1*o1fw[ci*AA+j];
    d3 += p2*o2cw[ci*AA+j]; d4 += p2*o2fw[ci*AA+j];
    #pragma unroll
    for(int e=0;e<9;e++) sspacc[e] += p2*spw[e*AA+j];
  }
  float sc1v=sigm(d1), sc2v=sigm(d3);
  float sf1o=__shfl(sigm(d2),o), sf2o=__shfl(sigm(d4),o);
  const float* wp = w + (size_t)(o*CC+ci)*9;
  float w9[9]; float m=0.f;
  #pragma unroll
  for(int e=0;e<9;e++){ w9[e]=wp[e]; m+=w9[e]; }
  m *= (1.0f/9.0f);
  float S1 = m * sc1v;
  float M[9];
  #pragma unroll
  for(int e=0;e<9;e++) M[e] = (w9[e]-m)*sc2v;
  #pragma unroll
  for(int off=32; off>0; off>>=1){
    S1 += __shfl_xor(S1, off);
    #pragma unroll
    for(int e=0;e<9;e++) M[e] += __shfl_xor(M[e], off);
  }
  if(ci==0){
    const float Dm[3][3] = {{2.f,2.f,2.f},{1.7320508075688772f,0.f,-1.7320508075688772f},{1.f,-2.f,1.f}};
    const float Di[3][3] = {{0.16666666666666666f,0.28867513459481287f,0.16666666666666666f},
                            {0.16666666666666666f,0.f,-0.3333333333333333f},
                            {0.16666666666666666f,-0.28867513459481287f,0.16666666666666666f}};
    float U[3][3], T[3][3], V[3][3], R[3][3];
    for(int k=0;k<3;k++)for(int n=0;n<3;n++) U[k][n]=Dm[k][0]*M[0*3+n]+Dm[k][1]*M[1*3+n]+Dm[k][2]*M[2*3+n];
    for(int k=0;k<3;k++)for(int l=0;l<3;l++) T[k][l]=(U[k][0]*Dm[l][0]+U[k][1]*Dm[l][1]+U[k][2]*Dm[l][2])*2.0f*sigm(sspacc[k*3+l]);
    for(int k=0;k<3;k++)for(int n=0;n<3;n++) V[k][n]=Di[k][0]*T[0][n]+Di[k][1]*T[1][n]+Di[k][2]*T[2][n];
    for(int k=0;k<3;k++)for(int l=0;l<3;l++) R[k][l]=V[k][0]*Di[l][0]+V[k][1]*Di[l][1]+V[k][2]*Di[l][2];
    float rr = ratio_p[0];
    float base = rr*4.0f*sf1o*S1;
    float w2f = (1.0f-rr)*4.0f*sf2o;
    #pragma unroll
    for(int e=0;e<9;e++) weff[(size_t)bo*9+e] = base + w2f*R[e/3][e%3];
  }
}

// ---------------- K3: iwt + transpose, channel-split: grid (b, h2, half) ----------------
// Each block handles 32 channels for rows h=2h2, 2h2+1.
__global__ __launch_bounds__(256) void k_iwtT(const float* __restrict__ HHb,
  const float* __restrict__ x, const float* __restrict__ weff,
  float* __restrict__ outT, ushort_t* __restrict__ outTbf)
{
  __shared__ __align__(16) char smem[25344 + 8320];
  float* hs  = (float*)smem;             // [32][3][66] = 25344 B
  float* xt  = (float*)smem;             // [32][129] = 16512 B (reused after conv)
  float* d_s = (float*)(smem + 25344);   // [32][65] = 8320 B
  int wg = blockIdx.x;
  int b = wg>>7; int idx7 = wg&127; int h2 = idx7>>1; int half = idx7&1;
  int t = threadIdx.x;
  // stage HH rows h2-1..h2+1 for this block's 32 channels, halo-zeroed (66 wide)
  for(int e=t; e<32*3*66; e+=256){
    int c_l = e/198; int rem = e - c_l*198; int r3 = rem/66; int wz = rem - r3*66;
    int r = h2 - 1 + r3; int w2 = wz - 1;
    int c = half*32 + c_l;
    float v = 0.f;
    if(r>=0 && r<KH && w2>=0 && w2<KW)
      v = HHb[((size_t)(b*CC+c))*(KH*KW) + r*KW + w2];
    hs[(c_l*3 + r3)*66 + wz] = v;
  }
  __syncthreads();
  // conv: 256 thr = (c_l 0..31, q 0..7), 8 w2 each
  {
    int c_l = t>>3, q = t&7;
    int c = half*32 + c_l;
    float wk[9];
    #pragma unroll
    for(int e=0;e<9;e++) wk[e] = weff[(size_t)(b*CC+c)*9+e];
    const float* hb = hs + c_l*198;
    #pragma unroll
    for(int j=0;j<8;j++){
      int w2 = q*8+j;
      float conv = 0.f;
      #pragma unroll
      for(int dh=0;dh<3;dh++){
        const float* hr = hb + dh*66 + w2;
        conv += wk[dh*3+0]*hr[0] + wk[dh*3+1]*hr[1] + wk[dh*3+2]*hr[2];
      }
      d_s[c_l*65+w2] = 0.5f*(conv - hb[1*66 + w2 + 1]);
    }
  }
  __syncthreads();
  #pragma unroll
  for(int r=0;r<2;r++){
    int h = 2*h2 + r;
    // stage x row h for this block's 32 channels (overwrites hs region)
    for(int e=t; e<32*WW; e+=256){
      int c_l=e>>7, w=e&127;
      xt[c_l*129+w] = x[((size_t)(b*CC+half*32+c_l)*HH_+h)*WW + w];
    }
    __syncthreads();
    float* dst = outT + ((size_t)(b*HH_+h))*WW*CC;
    ushort_t* dstb = outTbf + ((size_t)(b*HH_+h))*130*CC;
    for(int e=t; e<32*WW; e+=256){
      int w=e>>5, c_l=e&31; int c = half*32 + c_l;
      float dv = d_s[c_l*65+(w>>1)];
      float val = 2.f*xt[c_l*129+w] + (((h + w)&1) ? -dv : dv);
      dst[w*CC + c] = val;
      dstb[(w+1)*CC + c] = f2bf(val);
    }
    if(t<64){ int c_l=t&31; int side=t>>5; dstb[(size_t)side*129*CC + half*32 + c_l] = 0; }
    __syncthreads();
  }
}

// ---------------- K4: fused offset-conv + dy + deform-sample GEMM + GN partials ----------------
// r14 structure (best measured): LDS-staged, double-buffered, float4 gathers.
__global__ __launch_bounds__(512) void k_dsfused(const float* __restrict__ outT,
  const ushort_t* __restrict__ outTbf, const ushort_t* __restrict__ dsWbf,
  const ushort_t* __restrict__ offAbf, const float* __restrict__ offb,
  const float* __restrict__ obg, const float* __restrict__ obb,
  const float* __restrict__ obm, const float* __restrict__ obv,
  const float* __restrict__ dsb, float* __restrict__ yout, float* __restrict__ pstats)
{
  __shared__ ushort_t S2a[2*8192];
  __shared__ int sb0[KSZ*128], sb1[KSZ*128];
  __shared__ float swr[KSZ*128];
  __shared__ float off_s[KSZ*128];
  __shared__ float dy_s[KSZ*128];
  int t = threadIdx.x;
  int wg = blockIdx.x; int sw = (wg&7)*64 + (wg>>3);   // XCD swizzle
  int b = sw>>7, h = sw&127;
  int lane = t&63, wid = t>>6;
  int arow = lane&15, kgrp = lane>>4;
  // ---- Phase A: offset conv (8 waves, wave = one 16-wide w tile) ----
  {
    f32x4 acc = (f32x4){0.f,0.f,0.f,0.f};
    #pragma unroll
    for(int s=0;s<18;s++){
      int tap = s>>1, chalf = s&1;
      int r = tap/3, dwp = tap%3;
      int hr = h - 1 + r;
      if(hr<0 || hr>=HH_) continue;
      bf16x8 aF = *(const bf16x8*)(offAbf + (s*16+arow)*32 + kgrp*8);
      const ushort_t* base = outTbf + ((size_t)(b*HH_+hr))*130*CC + chalf*32 + kgrp*8;
      int wp = (wid<<4) + arow + dwp;
      bf16x8 bF = *(const bf16x8*)(base + (size_t)wp*CC);
      acc = __builtin_amdgcn_mfma_f32_16x16x32_bf16(aF, bF, acc, 0,0,0);
    }
    #pragma unroll
    for(int r=0;r<4;r++){
      int co = kgrp*4+r;
      if(co<KSZ) off_s[co*128 + (wid<<4) + arow] = acc[r];
    }
  }
  __syncthreads();
  // ---- Phase B: BN + tanh + cumsum ----
  if(t<128){
    int w = t;
    float y[KSZ];
    #pragma unroll
    for(int k=0;k<KSZ;k++){
      float sc = obg[k]*rsqrtf(obv[k]+EPSV);
      float sh = obb[k]-obm[k]*sc;
      y[k] = tanhf((off_s[k*128+w]+offb[k])*sc+sh);
    }
    dy_s[      w]=y[0]+y[1]+y[2]; dy_s[128+w]=y[1]+y[2]; dy_s[256+w]=y[2];
    dy_s[384+w]=0.f; dy_s[512+w]=y[4]; dy_s[640+w]=y[4]+y[5]; dy_s[768+w]=y[4]+y[5]+y[6];
  }
  __syncthreads();
  // ---- Phase C: sample meta ----
  for(int e=t; e<KSZ*128; e+=512){
    int k = e>>7, w = e&127;
    float dv = dy_s[e];
    float r = fminf(fmaxf((float)h + dv, 0.f), 127.f);
    float rf = floorf(r); int r0=(int)rf; float wr=r-rf; int r1=min(r0+1,127);
    int c = min(max(w+k-3,0),127);
    sb0[k*128+w] = ((b*HH_+r0)*WW+c)*CC;
    sb1[k*128+w] = ((b*HH_+r1)*WW+c)*CC;
    swr[k*128+w] = wr;
  }
  __syncthreads();
  // ---- Phase D: K-chunked double-buffered sample + MFMA GEMM (float4 gathers) ----
  int cg2 = wid&3, wh = wid>>2;
  int rsub = lane>>4;          // 0..3: row within 4-row group
  int ciq  = (lane&15)<<2;     // 0,4,...,60: ci quad
  // prologue: fill chunk 0
  {
    ushort_t* buf = S2a;
    #pragma unroll
    for(int i=0;i<4;i++){
      int p = (wid<<4) + i*4 + rsub;
      float4 v0 = *(const float4*)(outT + sb0[p] + ciq);
      float4 v1 = *(const float4*)(outT + sb1[p] + ciq);
      float wr = swr[p];
      unsigned lo = (unsigned)f2bf(v0.x + wr*(v1.x-v0.x)) | ((unsigned)f2bf(v0.y + wr*(v1.y-v0.y))<<16);
      unsigned hi = (unsigned)f2bf(v0.z + wr*(v1.z-v0.z)) | ((unsigned)f2bf(v0.w + wr*(v1.w-v0.w))<<16);
      int off = (p*128 + ciq*2) ^ ((p&7)<<4);
      *(uint2*)((char*)buf + off) = make_uint2(lo,hi);
    }
  }
  __syncthreads();
  f32x4 acc[4];
  #pragma unroll
  for(int nt=0;nt<4;nt++) acc[nt] = (f32x4){0.f,0.f,0.f,0.f};
  int bufs = 0;
  for(int k=0;k<KSZ;k++){
    if(k+1<KSZ){
      ushort_t* nb = S2a + (bufs^1)*8192;
      #pragma unroll
      for(int i=0;i<4;i++){
        int p = (wid<<4) + i*4 + rsub;
        int e = (k+1)*128 + p;
        float4 v0 = *(const float4*)(outT + sb0[e] + ciq);
        float4 v1 = *(const float4*)(outT + sb1[e] + ciq);
        float wr = swr[e];
        unsigned lo = (unsigned)f2bf(v0.x + wr*(v1.x-v0.x)) | ((unsigned)f2bf(v0.y + wr*(v1.y-v0.y))<<16);
        unsigned hi = (unsigned)f2bf(v0.z + wr*(v1.z-v0.z)) | ((unsigned)f2bf(v0.w + wr*(v1.w-v0.w))<<16);
        int off = (p*128 + ciq*2) ^ ((p&7)<<4);
        *(uint2*)((char*)nb + off) = make_uint2(lo,hi);
      }
    }
    const ushort_t* cb = S2a + bufs*8192;
    #pragma unroll
    for(int nt=0;nt<4;nt++){
      int pos = (wh<<6) + (nt<<4) + arow;
      int i0 = (pos<<6) + kgrp*8;
      int sz = (pos&7)<<3;
      bf16x8 b0 = *(const bf16x8*)(cb + (i0 ^ sz));
      bf16x8 b1 = *(const bf16x8*)(cb + ((i0+32) ^ sz));
      const ushort_t* Wp = dsWbf + (size_t)((cg2<<4)+arow)*KTOT + (k<<6) + kgrp*8;
      bf16x8 a0 = *(const bf16x8*)Wp;
      bf16x8 a1 = *(const bf16x8*)(Wp+32);
      acc[nt] = __builtin_amdgcn_mfma_f32_16x16x32_bf16(a0, b0, acc[nt], 0,0,0);
      acc[nt] = __builtin_amdgcn_mfma_f32_16x16x32_bf16(a1, b1, acc[nt], 0,0,0);
    }
    __syncthreads();
    bufs ^= 1;
  }
  // ---- epilogue: y + GN partials ----
  float vs[4]={0.f,0.f,0.f,0.f}, vq[4]={0.f,0.f,0.f,0.f};
  #pragma unroll
  for(int r=0;r<4;r++){
    int co = (cg2<<4) + kgrp*4 + r;
    float bias = dsb[co];
    #pragma unroll
    for(int nt=0;nt<4;nt++){
      float y = acc[nt][r] + bias;
      int wcol = (wh<<6) + (nt<<4) + arow;
      yout[((size_t)(b*CC+co)*HH_ + h)*WW + wcol] = y;
      vs[r] += y; vq[r] += y*y;
    }
  }
  #pragma unroll
  for(int m=1;m<16;m<<=1){
    #pragma unroll
    for(int r=0;r<4;r++){ vs[r]+=__shfl_xor(vs[r],m); vq[r]+=__shfl_xor(vq[r],m); }
  }
  if(arow==0){
    #pragma unroll
    for(int r=0;r<4;r++){
      int co = (cg2<<4)+kgrp*4+r;
      int pi = (b*CC+co)*256 + h*2 + wh;
      pstats[pi] = vs[r];
      pstats[65536+pi] = vq[r];
    }
  }
}

// ---------------- K5: reduce GN partials -> group stats ----------------
__global__ __launch_bounds__(256) void k_gnfin2(const float* __restrict__ pstats,
                                                float* __restrict__ gstat){
  int bg = blockIdx.x; int b = bg>>4, g = bg&15; int t = threadIdx.x;
  float s=0.f, q=0.f;
  #pragma unroll
  for(int c4=0;c4<4;c4++){
    int base = (b*CC + g*4+c4)*256;
    s += pstats[base + t];
    q += pstats[65536 + base + t];
  }
  for(int o=32;o>0;o>>=1){ s+=__shfl_down(s,o); q+=__shfl_down(q,o); }
  __shared__ float ls[4], lq[4];
  if((t&63)==0){ ls[t>>6]=s; lq[t>>6]=q; }
  __syncthreads();
  if(t==0){
    float S=ls[0]+ls[1]+ls[2]+ls[3], Q=lq[0]+lq[1]+lq[2]+lq[3];
    float inv = 1.0f/(4.0f*HPW);
    float mu = S*inv; float var = Q*inv - mu*mu;
    gstat[bg*2]=mu; gstat[bg*2+1]=rsqrtf(var+EPSV);
  }
}

// ---------------- K6: apply GN + affine + relu in place ----------------
__global__ void k_gnapply(float* __restrict__ y, const float* __restrict__ gstat,
  const float* __restrict__ gg, const float* __restrict__ gb){
  int idx = blockIdx.x*256 + threadIdx.x;
  float4* p = (float4*)y;
  int bc = idx >> 12;
  int b = bc>>6, c = bc&63;
  int gi = b*16 + (c>>2);
  float mu = gstat[gi*2], rstd = gstat[gi*2+1];
  float sc = rstd*gg[c], sh = gb[c]-mu*sc;
  float4 v = p[idx];
  v.x = fmaxf(v.x*sc+sh, 0.f);
  v.y = fmaxf(v.y*sc+sh, 0.f);
  v.z = fmaxf(v.z*sc+sh, 0.f);
  v.w = fmaxf(v.w*sc+sh, 0.f);
  p[idx] = v;
}

extern "C" void kernel_launch(void* const* d_in, const int* in_sizes, int n_in,
                              void* d_out, int out_size, void* d_ws, size_t ws_size,
                              hipStream_t stream) {
  const float* x      = (const float*)d_in[0];
  const float* weight = (const float*)d_in[1];
  const float* ratio  = (const float*)d_in[2];
  const float* o1fc   = (const float*)d_in[3];
  const float* o1g    = (const float*)d_in[4];
  const float* o1b    = (const float*)d_in[5];
  const float* o1m    = (const float*)d_in[6];
  const float* o1v    = (const float*)d_in[7];
  const float* o1cw   = (const float*)d_in[8];
  const float* o1cb   = (const float*)d_in[9];
  const float* o1fw   = (const float*)d_in[10];
  const float* o1fb   = (const float*)d_in[11];
  const float* o2fc   = (const float*)d_in[12];
  const float* o2g    = (const float*)d_in[13];
  const float* o2b    = (const float*)d_in[14];
  const float* o2m    = (const float*)d_in[15];
  const float* o2v    = (const float*)d_in[16];
  const float* o2cw   = (const float*)d_in[17];
  const float* o2cb   = (const float*)d_in[18];
  const float* o2fw   = (const float*)d_in[19];
  const float* o2fb   = (const float*)d_in[20];
  const float* spw    = (const float*)d_in[21];
  const float* spb    = (const float*)d_in[22];
  const float* offw   = (const float*)d_in[23];
  const float* offb   = (const float*)d_in[24];
  const float* obg    = (const float*)d_in[25];
  const float* obb    = (const float*)d_in[26];
  const float* obm    = (const float*)d_in[27];
  const float* obv    = (const float*)d_in[28];
  const float* dsw    = (const float*)d_in[29];
  const float* dsb    = (const float*)d_in[30];
  const float* gng    = (const float*)d_in[31];
  const float* gnb    = (const float*)d_in[32];

  float* ws    = (float*)d_ws;
  float* HHb   = ws;                            // 1048576
  float* partial = ws + 1048576;                // 512
  float* weff  = ws + 1049088;                  // 2304
  float* gstat = ws + 1051392;                  // 128
  ushort_t* dsWbf  = (ushort_t*)(ws + 1051520); // 28672 shorts
  ushort_t* offAbf = (ushort_t*)(ws + 1065856); // 9216 shorts
  float* pstats= ws + 1070464;                  // 131072
  float* outT  = ws + 1201536;                  // 4194304
  ushort_t* outTbf = (ushort_t*)(ws + 5395840); // 4*128*130*64 shorts
  float* outb  = (float*)d_out;

  k_dwt0<<<512,512,0,stream>>>(x, dsw, offw, HHb, partial, dsWbf, offAbf);
  k_weff2<<<256,64,0,stream>>>(partial, weight, ratio,
    o1fc,o1g,o1b,o1m,o1v,o1cw,o1cb,o1fw,o1fb,
    o2fc,o2g,o2b,o2m,o2v,o2cw,o2cb,o2fw,o2fb,
    spw,spb, weff);
  k_iwtT<<<512,256,0,stream>>>(HHb, x, weff, outT, outTbf);
  k_dsfused<<<512,512,0,stream>>>(outT, outTbf, dsWbf, offAbf,
    offb, obg, obb, obm, obv, dsb, outb, pstats);
  k_gnfin2<<<64,256,0,stream>>>(pstats, gstat);
  k_gnapply<<<4096,256,0,stream>>>(outb, gstat, gng, gnb);
}

// Round 18
// 79.882 us; speedup vs baseline: 1.4743x; 1.0756x over previous
//
#include <hip/hip_runtime.h>
#include <math.h>

#define BB 4
#define CC 64
#define HH_ 128
#define WW 128
#define HPW (HH_*WW)     // 16384
#define KH 64
#define KW 64
#define KSZ 7
#define AA 16
#define EPSV 1e-5f
#define KTOT 448         // 7*64

typedef __attribute__((ext_vector_type(8))) short bf16x8;
typedef __attribute__((ext_vector_type(4))) float f32x4;
typedef unsigned short ushort_t;

__device__ __forceinline__ float sigm(float x){ return 1.0f/(1.0f+expf(-x)); }
__device__ __forceinline__ unsigned short f2bf(float f){
  unsigned u = __float_as_uint(f);
  return (unsigned short)((u + 0x7fffu + ((u>>16)&1u)) >> 16);
}
__device__ __forceinline__ float bf2f(unsigned short s){
  return __uint_as_float(((unsigned)s)<<16);
}

// ---------------- K1: prep + DWT-HH + mean partials (512 x 512) ----------------
__global__ __launch_bounds__(512) void k_dwt0(const float* __restrict__ x,
  const float* __restrict__ dsw, const float* __restrict__ offw,
  float* __restrict__ HHb, float* __restrict__ partial,
  ushort_t* __restrict__ dsWbf, ushort_t* __restrict__ offAbf)
{
  int t = threadIdx.x; int wg = blockIdx.x;
  int idx = wg*512 + t;
  if(idx < CC*KTOT){
    int co = idx/KTOT; int K = idx%KTOT; int k = K>>6; int ci = K&63;
    dsWbf[idx] = f2bf(dsw[(size_t)(co*CC+ci)*KSZ + k]);
  } else {
    int j2 = idx - CC*KTOT;
    if(j2 < 18*16*32){
      int kl = j2&31; int co = (j2>>5)&15; int s = j2>>9;
      int tap = s>>1; int ci = (s&1)*32 + kl;
      float v = 0.f;
      if(co<KSZ) v = offw[((size_t)co*CC + ci)*9 + tap];
      offAbf[j2] = f2bf(v);
    }
  }
  int lane = t&63, wid = t>>6;
  int e0 = wg*2048 + t*4;
  int bc = e0>>12; int h2 = (e0>>6)&63; int w0 = e0&63;
  const float* xp = x + (size_t)bc*HPW;
  float4 a0 = *(const float4*)(xp + (2*h2)*WW + 2*w0);
  float4 a1 = *(const float4*)(xp + (2*h2)*WW + 2*w0 + 4);
  float4 b0 = *(const float4*)(xp + (2*h2+1)*WW + 2*w0);
  float4 b1 = *(const float4*)(xp + (2*h2+1)*WW + 2*w0 + 4);
  float4 hh;
  hh.x = 0.5f*(a0.x - b0.x - a0.y + b0.y);
  hh.y = 0.5f*(a0.z - b0.z - a0.w + b0.w);
  hh.z = 0.5f*(a1.x - b1.x - a1.y + b1.y);
  hh.w = 0.5f*(a1.z - b1.z - a1.w + b1.w);
  *(float4*)(HHb + e0) = hh;
  float s = a0.x+a0.y+a0.z+a0.w + a1.x+a1.y+a1.z+a1.w
          + b0.x+b0.y+b0.z+b0.w + b1.x+b1.y+b1.z+b1.w;
  for(int o=32;o>0;o>>=1) s += __shfl_down(s,o);
  __shared__ float ls[8];
  if(lane==0) ls[wid] = s;
  __syncthreads();
  if(t==0){
    float tot=0.f;
    #pragma unroll
    for(int k2=0;k2<8;k2++) tot += ls[k2];
    partial[wg] = tot;
  }
}

// ---------------- K2: attention + weff, grid (b,o), 64 thr ----------------
__global__ __launch_bounds__(64) void k_weff2(const float* __restrict__ partial,
  const float* __restrict__ w, const float* __restrict__ ratio_p,
  const float* __restrict__ o1fc, const float* __restrict__ o1g,const float* __restrict__ o1b,
  const float* __restrict__ o1m,const float* __restrict__ o1v,
  const float* __restrict__ o1cw,const float* __restrict__ o1cb,
  const float* __restrict__ o1fw,const float* __restrict__ o1fb,
  const float* __restrict__ o2fc, const float* __restrict__ o2g,const float* __restrict__ o2b,
  const float* __restrict__ o2m,const float* __restrict__ o2v,
  const float* __restrict__ o2cw,const float* __restrict__ o2cb,
  const float* __restrict__ o2fw,const float* __restrict__ o2fb,
  const float* __restrict__ spw,const float* __restrict__ spb,
  float* __restrict__ weff)
{
  int bo = blockIdx.x; int b = bo>>6, o = bo&63; int ci = threadIdx.x;
  int bc = b*CC+ci;
  float g_own = (partial[2*bc] + partial[2*bc+1]) * (1.0f/HPW);
  float d1=o1cb[ci], d2=o1fb[ci], d3=o2cb[ci], d4=o2fb[ci];
  float sspacc[9];
  #pragma unroll
  for(int e=0;e<9;e++) sspacc[e]=spb[e];
  for(int j=0;j<AA;j++){
    float p1 = g_own * o1fc[j*CC+ci];
    float p2 = g_own * o2fc[j*CC+ci];
    #pragma unroll
    for(int off=32;off>0;off>>=1){ p1+=__shfl_xor(p1,off); p2+=__shfl_xor(p2,off); }
    p1 = (p1-o1m[j])*rsqrtf(o1v[j]+EPSV)*o1g[j]+o1b[j]; p1=fmaxf(p1,0.f);
    p2 = (p2-o2m[j])*rsqrtf(o2v[j]+EPSV)*o2g[j]+o2b[j]; p2=fmaxf(p2,0.f);
    d1 += p1*o1cw[ci*AA+j]; d2 += p1*o1fw[ci*AA+j];
    d3 += p2*o2cw[ci*AA+j]; d4 += p2*o2fw[ci*AA+j];
    #pragma unroll
    for(int e=0;e<9;e++) sspacc[e] += p2*spw[e*AA+j];
  }
  float sc1v=sigm(d1), sc2v=sigm(d3);
  float sf1o=__shfl(sigm(d2),o), sf2o=__shfl(sigm(d4),o);
  const float* wp = w + (size_t)(o*CC+ci)*9;
  float w9[9]; float m=0.f;
  #pragma unroll
  for(int e=0;e<9;e++){ w9[e]=wp[e]; m+=w9[e]; }
  m *= (1.0f/9.0f);
  float S1 = m * sc1v;
  float M[9];
  #pragma unroll
  for(int e=0;e<9;e++) M[e] = (w9[e]-m)*sc2v;
  #pragma unroll
  for(int off=32; off>0; off>>=1){
    S1 += __shfl_xor(S1, off);
    #pragma unroll
    for(int e=0;e<9;e++) M[e] += __shfl_xor(M[e], off);
  }
  if(ci==0){
    const float Dm[3][3] = {{2.f,2.f,2.f},{1.7320508075688772f,0.f,-1.7320508075688772f},{1.f,-2.f,1.f}};
    const float Di[3][3] = {{0.16666666666666666f,0.28867513459481287f,0.16666666666666666f},
                            {0.16666666666666666f,0.f,-0.3333333333333333f},
                            {0.16666666666666666f,-0.28867513459481287f,0.16666666666666666f}};
    float U[3][3], T[3][3], V[3][3], R[3][3];
    for(int k=0;k<3;k++)for(int n=0;n<3;n++) U[k][n]=Dm[k][0]*M[0*3+n]+Dm[k][1]*M[1*3+n]+Dm[k][2]*M[2*3+n];
    for(int k=0;k<3;k++)for(int l=0;l<3;l++) T[k][l]=(U[k][0]*Dm[l][0]+U[k][1]*Dm[l][1]+U[k][2]*Dm[l][2])*2.0f*sigm(sspacc[k*3+l]);
    for(int k=0;k<3;k++)for(int n=0;n<3;n++) V[k][n]=Di[k][0]*T[0][n]+Di[k][1]*T[1][n]+Di[k][2]*T[2][n];
    for(int k=0;k<3;k++)for(int l=0;l<3;l++) R[k][l]=V[k][0]*Di[l][0]+V[k][1]*Di[l][1]+V[k][2]*Di[l][2];
    float rr = ratio_p[0];
    float base = rr*4.0f*sf1o*S1;
    float w2f = (1.0f-rr)*4.0f*sf2o;
    #pragma unroll
    for(int e=0;e<9;e++) weff[(size_t)bo*9+e] = base + w2f*R[e/3][e%3];
  }
}

// ---------------- K3: iwt + transpose (bf16 only), grid (b, h2, half) ----------------
__global__ __launch_bounds__(256) void k_iwtT(const float* __restrict__ HHb,
  const float* __restrict__ x, const float* __restrict__ weff,
  ushort_t* __restrict__ outTbf)
{
  __shared__ __align__(16) char smem[25344 + 8320];
  float* hs  = (float*)smem;             // [32][3][66]
  float* xt  = (float*)smem;             // [32][129] (reused after conv)
  float* d_s = (float*)(smem + 25344);   // [32][65]
  int wg = blockIdx.x;
  int b = wg>>7; int idx7 = wg&127; int h2 = idx7>>1; int half = idx7&1;
  int t = threadIdx.x;
  for(int e=t; e<32*3*66; e+=256){
    int c_l = e/198; int rem = e - c_l*198; int r3 = rem/66; int wz = rem - r3*66;
    int r = h2 - 1 + r3; int w2 = wz - 1;
    int c = half*32 + c_l;
    float v = 0.f;
    if(r>=0 && r<KH && w2>=0 && w2<KW)
      v = HHb[((size_t)(b*CC+c))*(KH*KW) + r*KW + w2];
    hs[(c_l*3 + r3)*66 + wz] = v;
  }
  __syncthreads();
  {
    int c_l = t>>3, q = t&7;
    int c = half*32 + c_l;
    float wk[9];
    #pragma unroll
    for(int e=0;e<9;e++) wk[e] = weff[(size_t)(b*CC+c)*9+e];
    const float* hb = hs + c_l*198;
    #pragma unroll
    for(int j=0;j<8;j++){
      int w2 = q*8+j;
      float conv = 0.f;
      #pragma unroll
      for(int dh=0;dh<3;dh++){
        const float* hr = hb + dh*66 + w2;
        conv += wk[dh*3+0]*hr[0] + wk[dh*3+1]*hr[1] + wk[dh*3+2]*hr[2];
      }
      d_s[c_l*65+w2] = 0.5f*(conv - hb[1*66 + w2 + 1]);
    }
  }
  __syncthreads();
  #pragma unroll
  for(int r=0;r<2;r++){
    int h = 2*h2 + r;
    for(int e=t; e<32*WW; e+=256){
      int c_l=e>>7, w=e&127;
      xt[c_l*129+w] = x[((size_t)(b*CC+half*32+c_l)*HH_+h)*WW + w];
    }
    __syncthreads();
    ushort_t* dstb = outTbf + ((size_t)(b*HH_+h))*130*CC;
    for(int e=t; e<32*WW; e+=256){
      int w=e>>5, c_l=e&31; int c = half*32 + c_l;
      float dv = d_s[c_l*65+(w>>1)];
      float val = 2.f*xt[c_l*129+w] + (((h + w)&1) ? -dv : dv);
      dstb[(w+1)*CC + c] = f2bf(val);
    }
    if(t<64){ int c_l=t&31; int side=t>>5; dstb[(size_t)side*129*CC + half*32 + c_l] = 0; }
    __syncthreads();
  }
}

// ---------------- K4: fused offset-conv + dy + deform-sample GEMM + GN partials ----------------
// r14 structure; gathers are bf16x8 from outTbf (2 issues/chunk/wave).
__global__ __launch_bounds__(512) void k_dsfused(
  const ushort_t* __restrict__ outTbf, const ushort_t* __restrict__ dsWbf,
  const ushort_t* __restrict__ offAbf, const float* __restrict__ offb,
  const float* __restrict__ obg, const float* __restrict__ obb,
  const float* __restrict__ obm, const float* __restrict__ obv,
  const float* __restrict__ dsb, float* __restrict__ yout, float* __restrict__ pstats)
{
  __shared__ ushort_t S2a[2*8192];
  __shared__ int sb0[KSZ*128], sb1[KSZ*128];
  __shared__ float swr[KSZ*128];
  __shared__ float off_s[KSZ*128];
  __shared__ float dy_s[KSZ*128];
  int t = threadIdx.x;
  int wg = blockIdx.x; int sw = (wg&7)*64 + (wg>>3);   // XCD swizzle
  int b = sw>>7, h = sw&127;
  int lane = t&63, wid = t>>6;
  int arow = lane&15, kgrp = lane>>4;
  // ---- Phase A: offset conv ----
  {
    f32x4 acc = (f32x4){0.f,0.f,0.f,0.f};
    #pragma unroll
    for(int s=0;s<18;s++){
      int tap = s>>1, chalf = s&1;
      int r = tap/3, dwp = tap%3;
      int hr = h - 1 + r;
      if(hr<0 || hr>=HH_) continue;
      bf16x8 aF = *(const bf16x8*)(offAbf + (s*16+arow)*32 + kgrp*8);
      const ushort_t* base = outTbf + ((size_t)(b*HH_+hr))*130*CC + chalf*32 + kgrp*8;
      int wp = (wid<<4) + arow + dwp;
      bf16x8 bF = *(const bf16x8*)(base + (size_t)wp*CC);
      acc = __builtin_amdgcn_mfma_f32_16x16x32_bf16(aF, bF, acc, 0,0,0);
    }
    #pragma unroll
    for(int r=0;r<4;r++){
      int co = kgrp*4+r;
      if(co<KSZ) off_s[co*128 + (wid<<4) + arow] = acc[r];
    }
  }
  __syncthreads();
  // ---- Phase B: BN + tanh + cumsum ----
  if(t<128){
    int w = t;
    float y[KSZ];
    #pragma unroll
    for(int k=0;k<KSZ;k++){
      float sc = obg[k]*rsqrtf(obv[k]+EPSV);
      float sh = obb[k]-obm[k]*sc;
      y[k] = tanhf((off_s[k*128+w]+offb[k])*sc+sh);
    }
    dy_s[      w]=y[0]+y[1]+y[2]; dy_s[128+w]=y[1]+y[2]; dy_s[256+w]=y[2];
    dy_s[384+w]=0.f; dy_s[512+w]=y[4]; dy_s[640+w]=y[4]+y[5]; dy_s[768+w]=y[4]+y[5]+y[6];
  }
  __syncthreads();
  // ---- Phase C: sample meta (short-unit addresses into padded outTbf) ----
  for(int e=t; e<KSZ*128; e+=512){
    int k = e>>7, w = e&127;
    float dv = dy_s[e];
    float r = fminf(fmaxf((float)h + dv, 0.f), 127.f);
    float rf = floorf(r); int r0=(int)rf; float wr=r-rf; int r1=min(r0+1,127);
    int c = min(max(w+k-3,0),127);
    sb0[e] = ((b*HH_+r0)*130 + (c+1))*CC;
    sb1[e] = ((b*HH_+r1)*130 + (c+1))*CC;
    swr[e] = wr;
  }
  __syncthreads();
  // ---- Phase D: K-chunked double-buffered sample + MFMA GEMM (bf16x8 gathers) ----
  int cg2 = wid&3, wh = wid>>2;
  int psub = lane>>3;          // 0..7: pos within 8-row group
  int ci8  = (lane&7)<<3;      // 0,8,...,56: ci octet
  auto fill = [&](int k, ushort_t* buf){
    #pragma unroll
    for(int j=0;j<2;j++){
      int p = (wid<<4) + j*8 + psub;        // GLOBAL pos 0..127
      int e = k*128 + p;
      bf16x8 r0 = *(const bf16x8*)(outTbf + sb0[e] + ci8);
      bf16x8 r1 = *(const bf16x8*)(outTbf + sb1[e] + ci8);
      float wr = swr[e];
      unsigned o4[4];
      #pragma unroll
      for(int q=0;q<4;q++){
        float a0 = bf2f((ushort_t)r0[2*q]),   b0v = bf2f((ushort_t)r1[2*q]);
        float a1 = bf2f((ushort_t)r0[2*q+1]), b1v = bf2f((ushort_t)r1[2*q+1]);
        o4[q] = (unsigned)f2bf(a0 + wr*(b0v-a0)) | ((unsigned)f2bf(a1 + wr*(b1v-a1))<<16);
      }
      int off = (p*128 + ci8*2) ^ ((p&7)<<4);
      *(uint4*)((char*)buf + off) = make_uint4(o4[0],o4[1],o4[2],o4[3]);
    }
  };
  fill(0, S2a);
  __syncthreads();
  f32x4 acc[4];
  #pragma unroll
  for(int nt=0;nt<4;nt++) acc[nt] = (f32x4){0.f,0.f,0.f,0.f};
  int bufs = 0;
  for(int k=0;k<KSZ;k++){
    if(k+1<KSZ) fill(k+1, S2a + (bufs^1)*8192);
    const ushort_t* cb = S2a + bufs*8192;
    #pragma unroll
    for(int nt=0;nt<4;nt++){
      int pos = (wh<<6) + (nt<<4) + arow;
      int i0 = (pos<<6) + kgrp*8;
      int sz = (pos&7)<<3;
      bf16x8 b0 = *(const bf16x8*)(cb + (i0 ^ sz));
      bf16x8 b1 = *(const bf16x8*)(cb + ((i0+32) ^ sz));
      const ushort_t* Wp = dsWbf + (size_t)((cg2<<4)+arow)*KTOT + (k<<6) + kgrp*8;
      bf16x8 a0 = *(const bf16x8*)Wp;
      bf16x8 a1 = *(const bf16x8*)(Wp+32);
      acc[nt] = __builtin_amdgcn_mfma_f32_16x16x32_bf16(a0, b0, acc[nt], 0,0,0);
      acc[nt] = __builtin_amdgcn_mfma_f32_16x16x32_bf16(a1, b1, acc[nt], 0,0,0);
    }
    __syncthreads();
    bufs ^= 1;
  }
  // ---- epilogue: y + GN partials ----
  float vs[4]={0.f,0.f,0.f,0.f}, vq[4]={0.f,0.f,0.f,0.f};
  #pragma unroll
  for(int r=0;r<4;r++){
    int co = (cg2<<4) + kgrp*4 + r;
    float bias = dsb[co];
    #pragma unroll
    for(int nt=0;nt<4;nt++){
      float y = acc[nt][r] + bias;
      int wcol = (wh<<6) + (nt<<4) + arow;
      yout[((size_t)(b*CC+co)*HH_ + h)*WW + wcol] = y;
      vs[r] += y; vq[r] += y*y;
    }
  }
  #pragma unroll
  for(int m=1;m<16;m<<=1){
    #pragma unroll
    for(int r=0;r<4;r++){ vs[r]+=__shfl_xor(vs[r],m); vq[r]+=__shfl_xor(vq[r],m); }
  }
  if(arow==0){
    #pragma unroll
    for(int r=0;r<4;r++){
      int co = (cg2<<4)+kgrp*4+r;
      int pi = (b*CC+co)*256 + h*2 + wh;
      pstats[pi] = vs[r];
      pstats[65536+pi] = vq[r];
    }
  }
}

// ---------------- K5: GN finalize (redundant per block) + apply + relu ----------------
__global__ __launch_bounds__(256) void k_gnapply(float* __restrict__ y,
  const float* __restrict__ pstats, const float* __restrict__ gg, const float* __restrict__ gb){
  int t = threadIdx.x;
  int idx = blockIdx.x*256 + t;
  int bc = idx >> 12;               // uniform within block (256 float4 per block)
  int b = bc>>6, c = bc&63;
  int g4 = c>>2;
  float s=0.f, q=0.f;
  int base = (b*CC + g4*4)*256;
  #pragma unroll
  for(int i=0;i<4;i++){
    s += pstats[base + i*256 + t];
    q += pstats[65536 + base + i*256 + t];
  }
  for(int o=32;o>0;o>>=1){ s+=__shfl_down(s,o); q+=__shfl_down(q,o); }
  __shared__ float ls[4], lq[4], bcast[2];
  if((t&63)==0){ ls[t>>6]=s; lq[t>>6]=q; }
  __syncthreads();
  if(t==0){
    float S=ls[0]+ls[1]+ls[2]+ls[3], Q=lq[0]+lq[1]+lq[2]+lq[3];
    float inv = 1.0f/(4.0f*HPW);
    float mu = S*inv; float var = Q*inv - mu*mu;
    bcast[0]=mu; bcast[1]=rsqrtf(var+EPSV);
  }
  __syncthreads();
  float mu = bcast[0], rstd = bcast[1];
  float sc = rstd*gg[c], sh = gb[c]-mu*sc;
  float4* p = (float4*)y;
  float4 v = p[idx];
  v.x = fmaxf(v.x*sc+sh, 0.f);
  v.y = fmaxf(v.y*sc+sh, 0.f);
  v.z = fmaxf(v.z*sc+sh, 0.f);
  v.w = fmaxf(v.w*sc+sh, 0.f);
  p[idx] = v;
}

extern "C" void kernel_launch(void* const* d_in, const int* in_sizes, int n_in,
                              void* d_out, int out_size, void* d_ws, size_t ws_size,
                              hipStream_t stream) {
  const float* x      = (const float*)d_in[0];
  const float* weight = (const float*)d_in[1];
  const float* ratio  = (const float*)d_in[2];
  const float* o1fc   = (const float*)d_in[3];
  const float* o1g    = (const float*)d_in[4];
  const float* o1b    = (const float*)d_in[5];
  const float* o1m    = (const float*)d_in[6];
  const float* o1v    = (const float*)d_in[7];
  const float* o1cw   = (const float*)d_in[8];
  const float* o1cb   = (const float*)d_in[9];
  const float* o1fw   = (const float*)d_in[10];
  const float* o1fb   = (const float*)d_in[11];
  const float* o2fc   = (const float*)d_in[12];
  const float* o2g    = (const float*)d_in[13];
  const float* o2b    = (const float*)d_in[14];
  const float* o2m    = (const float*)d_in[15];
  const float* o2v    = (const float*)d_in[16];
  const float* o2cw   = (const float*)d_in[17];
  const float* o2cb   = (const float*)d_in[18];
  const float* o2fw   = (const float*)d_in[19];
  const float* o2fb   = (const float*)d_in[20];
  const float* spw    = (const float*)d_in[21];
  const float* spb    = (const float*)d_in[22];
  const float* offw   = (const float*)d_in[23];
  const float* offb   = (const float*)d_in[24];
  const float* obg    = (const float*)d_in[25];
  const float* obb    = (const float*)d_in[26];
  const float* obm    = (const float*)d_in[27];
  const float* obv    = (const float*)d_in[28];
  const float* dsw    = (const float*)d_in[29];
  const float* dsb    = (const float*)d_in[30];
  const float* gng    = (const float*)d_in[31];
  const float* gnb    = (const float*)d_in[32];

  float* ws    = (float*)d_ws;
  float* HHb   = ws;                            // 1048576
  float* partial = ws + 1048576;                // 512
  float* weff  = ws + 1049088;                  // 2304
  ushort_t* dsWbf  = (ushort_t*)(ws + 1051392); // 28672 shorts
  ushort_t* offAbf = (ushort_t*)(ws + 1065728); // 9216 shorts
  float* pstats= ws + 1070336;                  // 131072
  ushort_t* outTbf = (ushort_t*)(ws + 1201408); // 4*128*130*64 shorts
  float* outb  = (float*)d_out;

  k_dwt0<<<512,512,0,stream>>>(x, dsw, offw, HHb, partial, dsWbf, offAbf);
  k_weff2<<<256,64,0,stream>>>(partial, weight, ratio,
    o1fc,o1g,o1b,o1m,o1v,o1cw,o1cb,o1fw,o1fb,
    o2fc,o2g,o2b,o2m,o2v,o2cw,o2cb,o2fw,o2fb,
    spw,spb, weff);
  k_iwtT<<<512,256,0,stream>>>(HHb, x, weff, outTbf);
  k_dsfused<<<512,512,0,stream>>>(outTbf, dsWbf, offAbf,
    offb, obg, obb, obm, obv, dsb, outb, pstats);
  k_gnapply<<<4096,256,0,stream>>>(outb, pstats, gng, gnb);
}